// Round 11
// baseline (1476.510 us; speedup 1.0000x reference)
//
#include <hip/hip_runtime.h>

// RelationAwareAttention: B=1, S=2048, D=1024, H=8. fp32 in / fp32 out.
// Raw reshape semantics: key(h,t) = x[8*(t&255)+h] @ attn_w[t>>8]
// Round-11: conflict-free LINEAR LDS chunk layout (chunk c: blk=c>>6, m=c&15,
// kb=(c>>4)&3; LDS addr c*8 u16; frag read = blk*512+lane*8 -> both staging
// writes and frag reads are 2-way (free, m136)). Round-10's map had 8-way
// conflicted reads (3.1M counter). Tile shapes kept from round 10.
// Split-bf16: PROD3 (AhBh+AhBl+AlBh) for rel/Kp/logits; PROD1 ctx/outproj.
// Batched attn_w transposes (grid.z=8); x-transpose hoisted if ws>=76MB.
// ws map (72 MiB + optional 4):
//   0 xh 4 | 4 xl | 8 relh | 12 rell | 16 awTh 16 | 32 awTl 16
//   48 Kp pair 8 (Ph aliases after logits) | 56 L 16
//   L aliases: tmph@56 tmpl@60 rw2Th@64 rw2Tl@66 (pre-loop);
//              ctxh@56 owTh@60 xTh@62 (post-softmax, per-head)
//   ws>=76MB: persistent xTh@72 (computed once).
// Fallback: ws<72M -> fp32 gemm64 path; ws<40M -> sentinel.

typedef unsigned short u16;
typedef short s16x8 __attribute__((ext_vector_type(8)));
typedef float f32x4 __attribute__((ext_vector_type(4)));

__device__ __forceinline__ float bf2f(u16 u) {
    union { unsigned int i; float f; } v; v.i = ((unsigned int)u) << 16; return v.f;
}
__device__ __forceinline__ u16 f2bf(float f) {
    unsigned int x = __float_as_uint(f);
    unsigned int r = x + 0x7fffu + ((x >> 16) & 1u);
    return (u16)(r >> 16);
}

__launch_bounds__(256)
__global__ void diag_k(float* __restrict__ out, int n, float code) {
    int i = blockIdx.x * 256 + threadIdx.x;
    if (i < n) out[i] = (i == 0) ? code : 0.f;
}

__launch_bounds__(256)
__global__ void expand_pair(const float* __restrict__ src, u16* __restrict__ hi,
                            u16* __restrict__ lo) {
    const size_t i = ((size_t)blockIdx.x * 256 + threadIdx.x) * 4;
    float4 v = *(const float4*)&src[i];
    ushort4 h, l;
    h.x = f2bf(v.x); l.x = f2bf(v.x - bf2f(h.x));
    h.y = f2bf(v.y); l.y = f2bf(v.y - bf2f(h.y));
    h.z = f2bf(v.z); l.z = f2bf(v.z - bf2f(h.z));
    h.w = f2bf(v.w); l.w = f2bf(v.w - bf2f(h.w));
    *(ushort4*)&hi[i] = h;
    *(ushort4*)&lo[i] = l;
}

// transpose fp32 [R][C] -> bf16 hi(/lo) [C][R]; grid.z indexes slabs of
// src_z/dst_z elements (batched attn_w heads; z=1 for single matrices)
__launch_bounds__(256)
__global__ void tr_pair(const float* __restrict__ src0, u16* __restrict__ dh0,
                        u16* __restrict__ dl0, int R, int C,
                        size_t src_z, size_t dst_z) {
    __shared__ float T[32][33];
    const float* src = src0 + (size_t)blockIdx.z * src_z;
    u16* dh = dh0 + (size_t)blockIdx.z * dst_z;
    u16* dl = dl0 ? dl0 + (size_t)blockIdx.z * dst_z : nullptr;
    const int bx = blockIdx.x, by = blockIdx.y;
    const int rr = threadIdx.x >> 3;
    const int cc = (threadIdx.x & 7) * 4;
    float4 v = *(const float4*)(src + (size_t)(by * 32 + rr) * C + bx * 32 + cc);
    T[rr][cc] = v.x; T[rr][cc + 1] = v.y; T[rr][cc + 2] = v.z; T[rr][cc + 3] = v.w;
    __syncthreads();
    float o0 = T[cc + 0][rr], o1 = T[cc + 1][rr], o2 = T[cc + 2][rr], o3 = T[cc + 3][rr];
    ushort4 h;
    h.x = f2bf(o0); h.y = f2bf(o1); h.z = f2bf(o2); h.w = f2bf(o3);
    size_t di = (size_t)(bx * 32 + rr) * R + by * 32 + cc;
    *(ushort4*)&dh[di] = h;
    if (dl) {
        ushort4 l;
        l.x = f2bf(o0 - bf2f(h.x)); l.y = f2bf(o1 - bf2f(h.y));
        l.z = f2bf(o2 - bf2f(h.z)); l.w = f2bf(o3 - bf2f(h.w));
        *(ushort4*)&dl[di] = l;
    }
}

__launch_bounds__(256)
__global__ void rel_l1_pair(const float* __restrict__ relations, const float* __restrict__ w1,
                            const float* __restrict__ b1, u16* __restrict__ th,
                            u16* __restrict__ tl) {
    const int s = blockIdx.x;
    const int d = threadIdx.x * 4;
    float4 rr = *(const float4*)(relations + s * 4);
    float4 w0 = *(const float4*)(w1 + 0 * 1024 + d);
    float4 w1r = *(const float4*)(w1 + 1 * 1024 + d);
    float4 w2r = *(const float4*)(w1 + 2 * 1024 + d);
    float4 w3r = *(const float4*)(w1 + 3 * 1024 + d);
    float4 bb = *(const float4*)(b1 + d);
    float o[4];
    o[0] = fmaxf(rr.x * w0.x + rr.y * w1r.x + rr.z * w2r.x + rr.w * w3r.x + bb.x, 0.f);
    o[1] = fmaxf(rr.x * w0.y + rr.y * w1r.y + rr.z * w2r.y + rr.w * w3r.y + bb.y, 0.f);
    o[2] = fmaxf(rr.x * w0.z + rr.y * w1r.z + rr.z * w2r.z + rr.w * w3r.z + bb.z, 0.f);
    o[3] = fmaxf(rr.x * w0.w + rr.y * w1r.w + rr.z * w2r.w + rr.w * w3r.w + bb.w, 0.f);
    ushort4 h, l;
    h.x = f2bf(o[0]); l.x = f2bf(o[0] - bf2f(h.x));
    h.y = f2bf(o[1]); l.y = f2bf(o[1] - bf2f(h.y));
    h.z = f2bf(o[2]); l.z = f2bf(o[2] - bf2f(h.z));
    h.w = f2bf(o[3]); l.w = f2bf(o[3] - bf2f(h.w));
    *(ushort4*)&th[(size_t)s * 1024 + d] = h;
    *(ushort4*)&tl[(size_t)s * 1024 + d] = l;
}

__launch_bounds__(256)
__global__ void init_out(const float* __restrict__ bias, float* __restrict__ oa) {
    const int s = blockIdx.x;
    const int d = threadIdx.x * 4;
    *(float4*)&oa[(size_t)s * 1024 + d] = *(const float4*)(bias + d);
}

// ============ MFMA GEMM v3: block (MI*32)x(NJ*32), BK=32, 4 waves (2x2) ======
// A [M][K], B [N][K] both K-contiguous bf16. Linear conflict-free LDS layout.
// MODE 0: plain. MODE 2: A row remap 8*((m0+r)&255)+head, B offset (m0>>8)*1M.
// PROD 3: AhBh+AhBl+AlBh. PROD 1: AhBh.
// OUT 0: fp32 store; 1: fp32 +=; 2: bf16-hi store; 3: bf16 pair (+bias).
template<int MI, int NJ, int MODE, int PROD, int OUT>
__launch_bounds__(256)
__global__ void mg3(const u16* __restrict__ Ah, const u16* __restrict__ Al,
                    const u16* __restrict__ Bh, const u16* __restrict__ Bl,
                    void* __restrict__ C, u16* __restrict__ C2,
                    const float* __restrict__ bias,
                    int K, int lda, int ldb, int ldc, int head) {
    __shared__ u16 sAh[MI * 1024];
    __shared__ u16 sBh[NJ * 1024];
    __shared__ u16 sAl[(PROD == 3) ? MI * 1024 : 8];
    __shared__ u16 sBl[(PROD == 3) ? NJ * 1024 : 8];
    const int tid = threadIdx.x;
    const int m0 = blockIdx.y * (MI * 32);
    const int n0 = blockIdx.x * (NJ * 32);
    const int w = tid >> 6, lane = tid & 63;
    const int wm = (w >> 1) * MI;    // first 16-row m-block of this wave
    const int wn = (w & 1) * NJ;     // first 16-row n-block
    const int fo = lane * 8;         // frag offset within a 512-u16 block

    size_t bofft = 0;
    if (MODE == 2) bofft = (size_t)(m0 >> 8) * 1048576;

    f32x4 acc[MI][NJ];
#pragma unroll
    for (int i = 0; i < MI; ++i)
#pragma unroll
        for (int j = 0; j < NJ; ++j) acc[i][j] = {0.f, 0.f, 0.f, 0.f};

    for (int k0 = 0; k0 < K; k0 += 32) {
        // ---- stage A: MI*128 chunks, c -> (blk=c>>6, m=c&15, kb=(c>>4)&3) ----
#pragma unroll
        for (int cb = 0; cb < MI * 128; cb += 256) {
            int c = cb + tid;
            int blk = c >> 6, m = c & 15, kb = (c >> 4) & 3;
            int rloc = blk * 16 + m;
            int grow = (MODE == 2) ? ((((m0 + rloc) & 255) << 3) + head) : (m0 + rloc);
            size_t ga = (size_t)grow * lda + k0 + kb * 8;
            *(uint4*)&sAh[c * 8] = *(const uint4*)(Ah + ga);
            if (PROD == 3) *(uint4*)&sAl[c * 8] = *(const uint4*)(Al + ga);
        }
        // ---- stage B: NJ*128 chunks ----
#pragma unroll
        for (int cb = 0; cb < NJ * 128; cb += 256) {
            int c = cb + tid;
            int blk = c >> 6, n = c & 15, kb = (c >> 4) & 3;
            size_t ga = bofft + (size_t)(n0 + blk * 16 + n) * ldb + k0 + kb * 8;
            *(uint4*)&sBh[c * 8] = *(const uint4*)(Bh + ga);
            if (PROD == 3) *(uint4*)&sBl[c * 8] = *(const uint4*)(Bl + ga);
        }
        __syncthreads();
        // ---- frags + MFMA ----
        s16x8 bh[NJ], bl[NJ];
#pragma unroll
        for (int j = 0; j < NJ; ++j) {
            bh[j] = *(const s16x8*)&sBh[(wn + j) * 512 + fo];
            if (PROD == 3) bl[j] = *(const s16x8*)&sBl[(wn + j) * 512 + fo];
        }
#pragma unroll
        for (int i = 0; i < MI; ++i) {
            s16x8 ah = *(const s16x8*)&sAh[(wm + i) * 512 + fo];
#pragma unroll
            for (int j = 0; j < NJ; ++j)
                acc[i][j] = __builtin_amdgcn_mfma_f32_16x16x32_bf16(ah, bh[j], acc[i][j], 0, 0, 0);
            if (PROD == 3) {
                s16x8 al = *(const s16x8*)&sAl[(wm + i) * 512 + fo];
#pragma unroll
                for (int j = 0; j < NJ; ++j) {
                    acc[i][j] = __builtin_amdgcn_mfma_f32_16x16x32_bf16(ah, bl[j], acc[i][j], 0, 0, 0);
                    acc[i][j] = __builtin_amdgcn_mfma_f32_16x16x32_bf16(al, bh[j], acc[i][j], 0, 0, 0);
                }
            }
        }
        __syncthreads();
    }

    // ---- epilogue: C col=lane&15, row=(lane>>4)*4+reg (verified m89/m91) ----
    const int cc = lane & 15, q = lane >> 4;
#pragma unroll
    for (int i = 0; i < MI; ++i) {
#pragma unroll
        for (int j = 0; j < NJ; ++j) {
            const int mb = m0 + (wm + i) * 16 + q * 4;
            const int nb = n0 + (wn + j) * 16 + cc;
            if (OUT == 0) {
                float* Cf = (float*)C;
#pragma unroll
                for (int r = 0; r < 4; ++r)
                    Cf[(size_t)(mb + r) * ldc + nb] = acc[i][j][r];
            } else if (OUT == 1) {
                float* Cf = (float*)C;
#pragma unroll
                for (int r = 0; r < 4; ++r)
                    Cf[(size_t)(mb + r) * ldc + nb] += acc[i][j][r];
            } else if (OUT == 2) {
                u16* Ch = (u16*)C;
#pragma unroll
                for (int r = 0; r < 4; ++r)
                    Ch[(size_t)(mb + r) * ldc + nb] = f2bf(acc[i][j][r]);
            } else {  // OUT == 3
                u16* Ch = (u16*)C;
                float bv = bias ? bias[nb] : 0.f;
#pragma unroll
                for (int r = 0; r < 4; ++r) {
                    float v = acc[i][j][r] + bv;
                    u16 h = f2bf(v);
                    Ch[(size_t)(mb + r) * ldc + nb] = h;
                    C2[(size_t)(mb + r) * ldc + nb] = f2bf(v - bf2f(h));
                }
            }
        }
    }
}

// ---------------- softmax: fp32 L row -> bf16-hi P row ----------------
__launch_bounds__(256)
__global__ void softmax_hi(const float* __restrict__ L, u16* __restrict__ Ph) {
    const int row = blockIdx.x;
    const float* p = L + (size_t)row * 2048;
    float4 v0 = ((const float4*)p)[threadIdx.x];
    float4 v1 = ((const float4*)p)[threadIdx.x + 256];
    float m = fmaxf(fmaxf(fmaxf(v0.x, v0.y), fmaxf(v0.z, v0.w)),
                    fmaxf(fmaxf(v1.x, v1.y), fmaxf(v1.z, v1.w)));
#pragma unroll
    for (int off = 32; off; off >>= 1) m = fmaxf(m, __shfl_xor(m, off));
    __shared__ float rm[4], rs[4];
    const int wave = threadIdx.x >> 6;
    if ((threadIdx.x & 63) == 0) rm[wave] = m;
    __syncthreads();
    m = fmaxf(fmaxf(rm[0], rm[1]), fmaxf(rm[2], rm[3]));
    v0.x = __expf(v0.x - m); v0.y = __expf(v0.y - m);
    v0.z = __expf(v0.z - m); v0.w = __expf(v0.w - m);
    v1.x = __expf(v1.x - m); v1.y = __expf(v1.y - m);
    v1.z = __expf(v1.z - m); v1.w = __expf(v1.w - m);
    float s = v0.x + v0.y + v0.z + v0.w + v1.x + v1.y + v1.z + v1.w;
#pragma unroll
    for (int off = 32; off; off >>= 1) s += __shfl_xor(s, off);
    if ((threadIdx.x & 63) == 0) rs[wave] = s;
    __syncthreads();
    s = rs[0] + rs[1] + rs[2] + rs[3];
    const float inv = 1.0f / s;
    ushort4 h0, h1;
    h0.x = f2bf(v0.x * inv); h0.y = f2bf(v0.y * inv);
    h0.z = f2bf(v0.z * inv); h0.w = f2bf(v0.w * inv);
    h1.x = f2bf(v1.x * inv); h1.y = f2bf(v1.y * inv);
    h1.z = f2bf(v1.z * inv); h1.w = f2bf(v1.w * inv);
    u16* o = Ph + (size_t)row * 2048;
    ((ushort4*)o)[threadIdx.x] = h0;
    ((ushort4*)o)[threadIdx.x + 256] = h1;
}

// ================= fallback: fp32 path (rounds 6-7, passing) =================
__launch_bounds__(256)
__global__ void rel_l1(const float* __restrict__ relations, const float* __restrict__ w1,
                       const float* __restrict__ b1, float* __restrict__ tmp) {
    const int s = blockIdx.x;
    const int d = threadIdx.x * 4;
    float4 rr = *(const float4*)(relations + s * 4);
    float4 w0 = *(const float4*)(w1 + 0 * 1024 + d);
    float4 w1r = *(const float4*)(w1 + 1 * 1024 + d);
    float4 w2r = *(const float4*)(w1 + 2 * 1024 + d);
    float4 w3r = *(const float4*)(w1 + 3 * 1024 + d);
    float4 bb = *(const float4*)(b1 + d);
    float o0 = fmaxf(rr.x * w0.x + rr.y * w1r.x + rr.z * w2r.x + rr.w * w3r.x + bb.x, 0.f);
    float o1 = fmaxf(rr.x * w0.y + rr.y * w1r.y + rr.z * w2r.y + rr.w * w3r.y + bb.y, 0.f);
    float o2 = fmaxf(rr.x * w0.z + rr.y * w1r.z + rr.z * w2r.z + rr.w * w3r.z + bb.z, 0.f);
    float o3 = fmaxf(rr.x * w0.w + rr.y * w1r.w + rr.z * w2r.w + rr.w * w3r.w + bb.w, 0.f);
    *(float4*)&tmp[(size_t)s * 1024 + d] = make_float4(o0, o1, o2, o3);
}

__launch_bounds__(256)
__global__ void softmax_rows(float* __restrict__ P) {
    const int row = blockIdx.x;
    float* p = P + (size_t)row * 2048;
    float4 v0 = ((const float4*)p)[threadIdx.x];
    float4 v1 = ((const float4*)p)[threadIdx.x + 256];
    float m = fmaxf(fmaxf(fmaxf(v0.x, v0.y), fmaxf(v0.z, v0.w)),
                    fmaxf(fmaxf(v1.x, v1.y), fmaxf(v1.z, v1.w)));
#pragma unroll
    for (int off = 32; off; off >>= 1) m = fmaxf(m, __shfl_xor(m, off));
    __shared__ float rm[4], rs[4];
    const int wave = threadIdx.x >> 6;
    if ((threadIdx.x & 63) == 0) rm[wave] = m;
    __syncthreads();
    m = fmaxf(fmaxf(rm[0], rm[1]), fmaxf(rm[2], rm[3]));
    v0.x = __expf(v0.x - m); v0.y = __expf(v0.y - m);
    v0.z = __expf(v0.z - m); v0.w = __expf(v0.w - m);
    v1.x = __expf(v1.x - m); v1.y = __expf(v1.y - m);
    v1.z = __expf(v1.z - m); v1.w = __expf(v1.w - m);
    float s = v0.x + v0.y + v0.z + v0.w + v1.x + v1.y + v1.z + v1.w;
#pragma unroll
    for (int off = 32; off; off >>= 1) s += __shfl_xor(s, off);
    if ((threadIdx.x & 63) == 0) rs[wave] = s;
    __syncthreads();
    s = rs[0] + rs[1] + rs[2] + rs[3];
    const float inv = 1.0f / s;
    v0.x *= inv; v0.y *= inv; v0.z *= inv; v0.w *= inv;
    v1.x *= inv; v1.y *= inv; v1.z *= inv; v1.w *= inv;
    ((float4*)p)[threadIdx.x] = v0;
    ((float4*)p)[threadIdx.x + 256] = v1;
}

constexpr int FBM = 64, FBN = 64, FBK = 16;

template<int MODE, bool ACC, bool TRC>
__launch_bounds__(256)
__global__ void gemm64(const float* __restrict__ A, const float* __restrict__ B,
                       float* __restrict__ C, const float* __restrict__ bias,
                       int M, int N, int K, int lda, int ldb, int ldc,
                       int head, size_t boff) {
    __shared__ float As[FBK][FBM + 4];
    __shared__ float Bs[FBK][FBN + 4];
    const int tid = threadIdx.x;
    const int tx = tid & 15;
    const int ty = tid >> 4;
    const int m0 = blockIdx.y * FBM;
    const int n0 = blockIdx.x * FBN;
    size_t bofft = boff;
    if (MODE == 2) bofft += (size_t)(m0 >> 8) * 1024 * 1024;
    const int ar = tid >> 2;
    const int ac = (tid & 3) << 2;
    int grow = m0 + ar;
    if (MODE == 2) grow = ((grow & 255) << 3) + head;
    const size_t abase = (size_t)grow * lda + ac;
    const int br = tid >> 4;
    const int bc = (tid & 15) << 2;
    const size_t bbase = bofft + (size_t)br * ldb + n0 + bc;
    float acc[4][4];
#pragma unroll
    for (int i = 0; i < 4; ++i)
#pragma unroll
        for (int j = 0; j < 4; ++j) acc[i][j] = 0.f;
    for (int k0 = 0; k0 < K; k0 += FBK) {
        float4 va = *(const float4*)(A + abase + k0);
        float4 vb = *(const float4*)(B + bbase + (size_t)k0 * ldb);
        As[ac + 0][ar] = va.x; As[ac + 1][ar] = va.y;
        As[ac + 2][ar] = va.z; As[ac + 3][ar] = va.w;
        *(float4*)&Bs[br][bc] = vb;
        __syncthreads();
#pragma unroll
        for (int k = 0; k < FBK; ++k) {
            float a[4], b[4];
            *(float4*)&a[0] = *(const float4*)&As[k][ty * 4];
            *(float4*)&b[0] = *(const float4*)&Bs[k][tx * 4];
#pragma unroll
            for (int i = 0; i < 4; ++i)
#pragma unroll
                for (int j = 0; j < 4; ++j)
                    acc[i][j] = fmaf(a[i], b[j], acc[i][j]);
        }
        __syncthreads();
    }
    if (TRC) {
#pragma unroll
        for (int j = 0; j < 4; ++j) {
            int cn = n0 + tx * 4 + j;
            size_t cidx = (size_t)cn * ldc + m0 + ty * 4;
            *(float4*)&C[cidx] = make_float4(acc[0][j], acc[1][j], acc[2][j], acc[3][j]);
        }
    } else {
        float bv[4] = {0.f, 0.f, 0.f, 0.f};
        if (bias) {
#pragma unroll
            for (int j = 0; j < 4; ++j) bv[j] = bias[n0 + tx * 4 + j];
        }
#pragma unroll
        for (int i = 0; i < 4; ++i) {
            int cm = m0 + ty * 4 + i;
            size_t cidx = (size_t)cm * ldc + n0 + tx * 4;
            float4 o = make_float4(acc[i][0] + bv[0], acc[i][1] + bv[1],
                                   acc[i][2] + bv[2], acc[i][3] + bv[3]);
            if (ACC) {
                float4 old = *(const float4*)&C[cidx];
                o.x += old.x; o.y += old.y; o.z += old.z; o.w += old.w;
            }
            *(float4*)&C[cidx] = o;
        }
    }
}

extern "C" void kernel_launch(void* const* d_in, const int* in_sizes, int n_in,
                              void* d_out, int out_size, void* d_ws, size_t ws_size,
                              hipStream_t stream) {
    const float* x      = (const float*)d_in[0];
    const float* rels   = (const float*)d_in[1];
    const float* re_w1  = (const float*)d_in[2];
    const float* re_b1  = (const float*)d_in[3];
    const float* re_w2  = (const float*)d_in[4];
    const float* re_b2  = (const float*)d_in[5];
    const float* attn_w = (const float*)d_in[6];
    const float* out_w  = (const float*)d_in[7];
    const float* out_b  = (const float*)d_in[8];
    float* out = (float*)d_out;

    bool dims_ok = (n_in == 9) &&
        in_sizes[0] == 2097152 && in_sizes[1] == 8192 && in_sizes[2] == 4096 &&
        in_sizes[3] == 1024 && in_sizes[4] == 1048576 && in_sizes[5] == 1024 &&
        in_sizes[6] == 8388608 && in_sizes[7] == 8388608 && in_sizes[8] == 1024 &&
        out_size == 2097152;
    const size_t MB = 1024 * 1024;
    if (!dims_ok || ws_size < 40 * MB) {
        float code = 16384.f + (dims_ok ? 0.f : 2048.f) + 1024.f;
        diag_k<<<dim3((out_size + 255) / 256), 256, 0, stream>>>(out, out_size, code);
        return;
    }

    if (ws_size >= 72 * MB) {
        char* W = (char*)d_ws;
        u16* xh    = (u16*)(W);
        u16* xl    = (u16*)(W + 4 * MB);
        u16* relh  = (u16*)(W + 8 * MB);
        u16* rell  = (u16*)(W + 12 * MB);
        u16* awTh  = (u16*)(W + 16 * MB);
        u16* awTl  = (u16*)(W + 32 * MB);
        u16* Kph   = (u16*)(W + 48 * MB);
        u16* Kpl   = (u16*)(W + 52 * MB);
        u16* Ph    = (u16*)(W + 48 * MB);
        float* L   = (float*)(W + 56 * MB);
        u16* tmph  = (u16*)(W + 56 * MB);
        u16* tmpl  = (u16*)(W + 60 * MB);
        u16* rw2Th = (u16*)(W + 64 * MB);
        u16* rw2Tl = (u16*)(W + 66 * MB);
        u16* ctxh  = (u16*)(W + 56 * MB);
        u16* owTh  = (u16*)(W + 60 * MB);
        const bool hoist_xT = (ws_size >= 76 * MB);
        u16* xTh = hoist_xT ? (u16*)(W + 72 * MB) : (u16*)(W + 62 * MB);

        expand_pair<<<dim3(2048), 256, 0, stream>>>(x, xh, xl);
        rel_l1_pair<<<dim3(2048), 256, 0, stream>>>(rels, re_w1, re_b1, tmph, tmpl);
        tr_pair<<<dim3(32, 32, 1), 256, 0, stream>>>(re_w2, rw2Th, rw2Tl, 1024, 1024, 0, 0);
        // rel = tmp @ re_w2 + re_b2 -> pair
        mg3<2, 2, 0, 3, 3><<<dim3(16, 32), 256, 0, stream>>>(
            tmph, tmpl, rw2Th, rw2Tl, relh, rell, re_b2, 1024, 1024, 1024, 1024, 0);
        // all 8 attn_w transposes batched
        tr_pair<<<dim3(32, 32, 8), 256, 0, stream>>>(attn_w, awTh, awTl, 1024, 1024,
                                                     1048576, 1048576);
        if (hoist_xT)
            tr_pair<<<dim3(32, 64, 1), 256, 0, stream>>>(x, xTh, nullptr, 2048, 1024, 0, 0);
        init_out<<<dim3(2048), 256, 0, stream>>>(out_b, out);
        for (int h = 0; h < 8; ++h) {
            // Kp[t][d] = x[8*(t&255)+h] @ attn_w[t>>8]
            mg3<2, 2, 2, 3, 3><<<dim3(16, 32), 256, 0, stream>>>(
                xh, xl, awTh, awTl, Kph, Kpl, nullptr, 1024, 1024, 1024, 1024, h);
            // L = rel @ Kp^T
            mg3<4, 2, 0, 3, 0><<<dim3(32, 16), 256, 0, stream>>>(
                relh, rell, Kph, Kpl, L, nullptr, nullptr, 1024, 1024, 1024, 2048, 0);
            softmax_hi<<<dim3(2048), 256, 0, stream>>>(L, Ph);
            tr_pair<<<dim3(32, 32, 1), 256, 0, stream>>>(
                out_w + (size_t)h * MB, owTh, nullptr, 1024, 1024, 0, 0);
            if (!hoist_xT)
                tr_pair<<<dim3(32, 64, 1), 256, 0, stream>>>(x, xTh, nullptr, 2048, 1024, 0, 0);
            // ctx = P @ x   (B = xT [d][t])
            mg3<2, 2, 0, 1, 2><<<dim3(16, 32), 256, 0, stream>>>(
                Ph, nullptr, xTh, nullptr, ctxh, nullptr, nullptr, 2048, 2048, 2048, 1024, 0);
            // out += ctx @ out_w[h]   (B = owT [n][d])
            mg3<2, 2, 0, 1, 1><<<dim3(16, 32), 256, 0, stream>>>(
                ctxh, nullptr, owTh, nullptr, out, nullptr, nullptr, 1024, 1024, 1024, 1024, 0);
        }
        return;
    }

    // ================= fallback: fp32 path =================
    float* ws  = (float*)d_ws;
    float* rel = ws;
    float* KpT = rel + 2097152;
    float* ctx = KpT + 2097152;
    float* L   = ctx + 2097152;
    float* tmp = L;

    rel_l1<<<dim3(2048), dim3(256), 0, stream>>>(rels, re_w1, re_b1, tmp);
    gemm64<0, false, false><<<dim3(16, 32), 256, 0, stream>>>(
        tmp, re_w2, rel, re_b2, 2048, 1024, 1024, 1024, 1024, 1024, 0, 0);
    init_out<<<dim3(2048), dim3(256), 0, stream>>>(out_b, out);
    for (int h = 0; h < 8; ++h) {
        gemm64<2, false, true><<<dim3(16, 32), 256, 0, stream>>>(
            x, attn_w, KpT, nullptr, 2048, 1024, 1024, 1024, 1024, 2048, h, 0);
        gemm64<0, false, false><<<dim3(32, 32), 256, 0, stream>>>(
            rel, KpT, L, nullptr, 2048, 2048, 1024, 1024, 2048, 2048, 0, 0);
        softmax_rows<<<dim3(2048), 256, 0, stream>>>(L);
        gemm64<0, false, false><<<dim3(16, 32), 256, 0, stream>>>(
            L, x, ctx, nullptr, 2048, 1024, 2048, 2048, 1024, 1024, 0, 0);
        gemm64<0, true, false><<<dim3(16, 32), 256, 0, stream>>>(
            ctx, out_w, out, nullptr, 2048, 1024, 1024, 1024, 1024, 1024,
            0, (size_t)h * 1024 * 1024);
    }
}

// Round 12
// 1371.771 us; speedup vs baseline: 1.0764x; 1.0764x over previous
//
#include <hip/hip_runtime.h>

// RelationAwareAttention: B=1, S=2048, D=1024, H=8. fp32 in / fp32 out.
// Raw reshape semantics: key(h,t) = x[8*(t&255)+h] @ attn_w[t>>8]
// Round-12: async staging via __builtin_amdgcn_global_load_lds width=16
// (m93->m97 lever: 1.69x). Round-11's linear LDS chunk layout is the
// prerequisite: chunk c = cb+tid is lane-contiguous, so the wave-uniform
// base (c&~63)*16B + lane*16B lands each lane's 16B exactly at chunk c.
// Conflicts measured 0 in round 11; bottleneck is latency (occ 18%, grid
// 512 = 2 blocks/CU) -> remove the staging VGPR round-trip + VALU work.
// Split-bf16: PROD3 (AhBh+AhBl+AlBh) rel/Kp/logits; PROD1 ctx/outproj.
// ws map (72 MiB + optional 4):
//   0 xh 4 | 4 xl | 8 relh | 12 rell | 16 awTh 16 | 32 awTl 16
//   48 Kp pair 8 (Ph aliases after logits) | 56 L 16
//   L aliases: tmph@56 tmpl@60 rw2Th@64 rw2Tl@66 (pre-loop);
//              ctxh@56 owTh@60 xTh@62 (post-softmax, per-head)
//   ws>=76MB: persistent xTh@72 (computed once).
// Fallback: ws<72M -> fp32 gemm64 path; ws<40M -> sentinel.

typedef unsigned short u16;
typedef short s16x8 __attribute__((ext_vector_type(8)));
typedef float f32x4 __attribute__((ext_vector_type(4)));

__device__ __forceinline__ float bf2f(u16 u) {
    union { unsigned int i; float f; } v; v.i = ((unsigned int)u) << 16; return v.f;
}
__device__ __forceinline__ u16 f2bf(float f) {
    unsigned int x = __float_as_uint(f);
    unsigned int r = x + 0x7fffu + ((x >> 16) & 1u);
    return (u16)(r >> 16);
}

// async 16B global -> LDS (wave-uniform lds base; lane i lands at base+i*16B)
__device__ __forceinline__ void gl_lds16(const u16* g, u16* lds_base_uniform) {
    __builtin_amdgcn_global_load_lds(
        (const __attribute__((address_space(1))) void*)g,
        (__attribute__((address_space(3))) void*)lds_base_uniform, 16, 0, 0);
}

__launch_bounds__(256)
__global__ void diag_k(float* __restrict__ out, int n, float code) {
    int i = blockIdx.x * 256 + threadIdx.x;
    if (i < n) out[i] = (i == 0) ? code : 0.f;
}

__launch_bounds__(256)
__global__ void expand_pair(const float* __restrict__ src, u16* __restrict__ hi,
                            u16* __restrict__ lo) {
    const size_t i = ((size_t)blockIdx.x * 256 + threadIdx.x) * 4;
    float4 v = *(const float4*)&src[i];
    ushort4 h, l;
    h.x = f2bf(v.x); l.x = f2bf(v.x - bf2f(h.x));
    h.y = f2bf(v.y); l.y = f2bf(v.y - bf2f(h.y));
    h.z = f2bf(v.z); l.z = f2bf(v.z - bf2f(h.z));
    h.w = f2bf(v.w); l.w = f2bf(v.w - bf2f(h.w));
    *(ushort4*)&hi[i] = h;
    *(ushort4*)&lo[i] = l;
}

// transpose fp32 [R][C] -> bf16 hi(/lo) [C][R]; grid.z slabs for batching
__launch_bounds__(256)
__global__ void tr_pair(const float* __restrict__ src0, u16* __restrict__ dh0,
                        u16* __restrict__ dl0, int R, int C,
                        size_t src_z, size_t dst_z) {
    __shared__ float T[32][33];
    const float* src = src0 + (size_t)blockIdx.z * src_z;
    u16* dh = dh0 + (size_t)blockIdx.z * dst_z;
    u16* dl = dl0 ? dl0 + (size_t)blockIdx.z * dst_z : nullptr;
    const int bx = blockIdx.x, by = blockIdx.y;
    const int rr = threadIdx.x >> 3;
    const int cc = (threadIdx.x & 7) * 4;
    float4 v = *(const float4*)(src + (size_t)(by * 32 + rr) * C + bx * 32 + cc);
    T[rr][cc] = v.x; T[rr][cc + 1] = v.y; T[rr][cc + 2] = v.z; T[rr][cc + 3] = v.w;
    __syncthreads();
    float o0 = T[cc + 0][rr], o1 = T[cc + 1][rr], o2 = T[cc + 2][rr], o3 = T[cc + 3][rr];
    ushort4 h;
    h.x = f2bf(o0); h.y = f2bf(o1); h.z = f2bf(o2); h.w = f2bf(o3);
    size_t di = (size_t)(bx * 32 + rr) * R + by * 32 + cc;
    *(ushort4*)&dh[di] = h;
    if (dl) {
        ushort4 l;
        l.x = f2bf(o0 - bf2f(h.x)); l.y = f2bf(o1 - bf2f(h.y));
        l.z = f2bf(o2 - bf2f(h.z)); l.w = f2bf(o3 - bf2f(h.w));
        *(ushort4*)&dl[di] = l;
    }
}

__launch_bounds__(256)
__global__ void rel_l1_pair(const float* __restrict__ relations, const float* __restrict__ w1,
                            const float* __restrict__ b1, u16* __restrict__ th,
                            u16* __restrict__ tl) {
    const int s = blockIdx.x;
    const int d = threadIdx.x * 4;
    float4 rr = *(const float4*)(relations + s * 4);
    float4 w0 = *(const float4*)(w1 + 0 * 1024 + d);
    float4 w1r = *(const float4*)(w1 + 1 * 1024 + d);
    float4 w2r = *(const float4*)(w1 + 2 * 1024 + d);
    float4 w3r = *(const float4*)(w1 + 3 * 1024 + d);
    float4 bb = *(const float4*)(b1 + d);
    float o[4];
    o[0] = fmaxf(rr.x * w0.x + rr.y * w1r.x + rr.z * w2r.x + rr.w * w3r.x + bb.x, 0.f);
    o[1] = fmaxf(rr.x * w0.y + rr.y * w1r.y + rr.z * w2r.y + rr.w * w3r.y + bb.y, 0.f);
    o[2] = fmaxf(rr.x * w0.z + rr.y * w1r.z + rr.z * w2r.z + rr.w * w3r.z + bb.z, 0.f);
    o[3] = fmaxf(rr.x * w0.w + rr.y * w1r.w + rr.z * w2r.w + rr.w * w3r.w + bb.w, 0.f);
    ushort4 h, l;
    h.x = f2bf(o[0]); l.x = f2bf(o[0] - bf2f(h.x));
    h.y = f2bf(o[1]); l.y = f2bf(o[1] - bf2f(h.y));
    h.z = f2bf(o[2]); l.z = f2bf(o[2] - bf2f(h.z));
    h.w = f2bf(o[3]); l.w = f2bf(o[3] - bf2f(h.w));
    *(ushort4*)&th[(size_t)s * 1024 + d] = h;
    *(ushort4*)&tl[(size_t)s * 1024 + d] = l;
}

__launch_bounds__(256)
__global__ void init_out(const float* __restrict__ bias, float* __restrict__ oa) {
    const int s = blockIdx.x;
    const int d = threadIdx.x * 4;
    *(float4*)&oa[(size_t)s * 1024 + d] = *(const float4*)(bias + d);
}

// ============ MFMA GEMM v4: block (MI*32)x(NJ*32), BK=32, 4 waves (2x2) ======
// A [M][K], B [N][K] K-contiguous bf16. Linear LDS chunks + async staging.
// MODE 0: plain. MODE 2: A row remap 8*((m0+r)&255)+head, B offset (m0>>8)*1M.
// PROD 3: AhBh+AhBl+AlBh. PROD 1: AhBh.
// OUT 0: fp32 store; 1: fp32 +=; 2: bf16-hi store; 3: bf16 pair (+bias).
template<int MI, int NJ, int MODE, int PROD, int OUT>
__launch_bounds__(256)
__global__ void mg4(const u16* __restrict__ Ah, const u16* __restrict__ Al,
                    const u16* __restrict__ Bh, const u16* __restrict__ Bl,
                    void* __restrict__ C, u16* __restrict__ C2,
                    const float* __restrict__ bias,
                    int K, int lda, int ldb, int ldc, int head) {
    __shared__ u16 sAh[MI * 1024];
    __shared__ u16 sBh[NJ * 1024];
    __shared__ u16 sAl[(PROD == 3) ? MI * 1024 : 64];
    __shared__ u16 sBl[(PROD == 3) ? NJ * 1024 : 64];
    const int tid = threadIdx.x;
    const int m0 = blockIdx.y * (MI * 32);
    const int n0 = blockIdx.x * (NJ * 32);
    const int w = tid >> 6, lane = tid & 63;
    const int wm = (w >> 1) * MI;
    const int wn = (w & 1) * NJ;
    const int fo = lane * 8;

    size_t bofft = 0;
    if (MODE == 2) bofft = (size_t)(m0 >> 8) * 1048576;

    f32x4 acc[MI][NJ];
#pragma unroll
    for (int i = 0; i < MI; ++i)
#pragma unroll
        for (int j = 0; j < NJ; ++j) acc[i][j] = {0.f, 0.f, 0.f, 0.f};

    for (int k0 = 0; k0 < K; k0 += 32) {
        // ---- stage A async: chunk c -> (blk=c>>6, m=c&15, kb=(c>>4)&3) ----
#pragma unroll
        for (int cb = 0; cb < MI * 128; cb += 256) {
            int c = cb + tid;
            int blk = c >> 6, m = c & 15, kb = (c >> 4) & 3;
            int rloc = blk * 16 + m;
            int grow = (MODE == 2) ? ((((m0 + rloc) & 255) << 3) + head) : (m0 + rloc);
            size_t ga = (size_t)grow * lda + k0 + kb * 8;
            gl_lds16(Ah + ga, &sAh[(size_t)(c & ~63) * 8]);
            if (PROD == 3) gl_lds16(Al + ga, &sAl[(size_t)(c & ~63) * 8]);
        }
        // ---- stage B async ----
#pragma unroll
        for (int cb = 0; cb < NJ * 128; cb += 256) {
            int c = cb + tid;
            int blk = c >> 6, n = c & 15, kb = (c >> 4) & 3;
            size_t ga = bofft + (size_t)(n0 + blk * 16 + n) * ldb + k0 + kb * 8;
            gl_lds16(Bh + ga, &sBh[(size_t)(c & ~63) * 8]);
            if (PROD == 3) gl_lds16(Bl + ga, &sBl[(size_t)(c & ~63) * 8]);
        }
        __syncthreads();   // drains vmcnt (global_load_lds) before LDS reads
        // ---- frags + MFMA ----
        s16x8 bh[NJ], bl[NJ];
#pragma unroll
        for (int j = 0; j < NJ; ++j) {
            bh[j] = *(const s16x8*)&sBh[(wn + j) * 512 + fo];
            if (PROD == 3) bl[j] = *(const s16x8*)&sBl[(wn + j) * 512 + fo];
        }
#pragma unroll
        for (int i = 0; i < MI; ++i) {
            s16x8 ah = *(const s16x8*)&sAh[(wm + i) * 512 + fo];
#pragma unroll
            for (int j = 0; j < NJ; ++j)
                acc[i][j] = __builtin_amdgcn_mfma_f32_16x16x32_bf16(ah, bh[j], acc[i][j], 0, 0, 0);
            if (PROD == 3) {
                s16x8 al = *(const s16x8*)&sAl[(wm + i) * 512 + fo];
#pragma unroll
                for (int j = 0; j < NJ; ++j) {
                    acc[i][j] = __builtin_amdgcn_mfma_f32_16x16x32_bf16(ah, bl[j], acc[i][j], 0, 0, 0);
                    acc[i][j] = __builtin_amdgcn_mfma_f32_16x16x32_bf16(al, bh[j], acc[i][j], 0, 0, 0);
                }
            }
        }
        __syncthreads();
    }

    // ---- epilogue: C col=lane&15, row=(lane>>4)*4+reg (verified m89/m91) ----
    const int cc = lane & 15, q = lane >> 4;
#pragma unroll
    for (int i = 0; i < MI; ++i) {
#pragma unroll
        for (int j = 0; j < NJ; ++j) {
            const int mb = m0 + (wm + i) * 16 + q * 4;
            const int nb = n0 + (wn + j) * 16 + cc;
            if (OUT == 0) {
                float* Cf = (float*)C;
#pragma unroll
                for (int r = 0; r < 4; ++r)
                    Cf[(size_t)(mb + r) * ldc + nb] = acc[i][j][r];
            } else if (OUT == 1) {
                float* Cf = (float*)C;
#pragma unroll
                for (int r = 0; r < 4; ++r)
                    Cf[(size_t)(mb + r) * ldc + nb] += acc[i][j][r];
            } else if (OUT == 2) {
                u16* Ch = (u16*)C;
#pragma unroll
                for (int r = 0; r < 4; ++r)
                    Ch[(size_t)(mb + r) * ldc + nb] = f2bf(acc[i][j][r]);
            } else {  // OUT == 3
                u16* Ch = (u16*)C;
                float bv = bias ? bias[nb] : 0.f;
#pragma unroll
                for (int r = 0; r < 4; ++r) {
                    float v = acc[i][j][r] + bv;
                    u16 h = f2bf(v);
                    Ch[(size_t)(mb + r) * ldc + nb] = h;
                    C2[(size_t)(mb + r) * ldc + nb] = f2bf(v - bf2f(h));
                }
            }
        }
    }
}

// ---------------- softmax: fp32 L row -> bf16-hi P row ----------------
__launch_bounds__(256)
__global__ void softmax_hi(const float* __restrict__ L, u16* __restrict__ Ph) {
    const int row = blockIdx.x;
    const float* p = L + (size_t)row * 2048;
    float4 v0 = ((const float4*)p)[threadIdx.x];
    float4 v1 = ((const float4*)p)[threadIdx.x + 256];
    float m = fmaxf(fmaxf(fmaxf(v0.x, v0.y), fmaxf(v0.z, v0.w)),
                    fmaxf(fmaxf(v1.x, v1.y), fmaxf(v1.z, v1.w)));
#pragma unroll
    for (int off = 32; off; off >>= 1) m = fmaxf(m, __shfl_xor(m, off));
    __shared__ float rm[4], rs[4];
    const int wave = threadIdx.x >> 6;
    if ((threadIdx.x & 63) == 0) rm[wave] = m;
    __syncthreads();
    m = fmaxf(fmaxf(rm[0], rm[1]), fmaxf(rm[2], rm[3]));
    v0.x = __expf(v0.x - m); v0.y = __expf(v0.y - m);
    v0.z = __expf(v0.z - m); v0.w = __expf(v0.w - m);
    v1.x = __expf(v1.x - m); v1.y = __expf(v1.y - m);
    v1.z = __expf(v1.z - m); v1.w = __expf(v1.w - m);
    float s = v0.x + v0.y + v0.z + v0.w + v1.x + v1.y + v1.z + v1.w;
#pragma unroll
    for (int off = 32; off; off >>= 1) s += __shfl_xor(s, off);
    if ((threadIdx.x & 63) == 0) rs[wave] = s;
    __syncthreads();
    s = rs[0] + rs[1] + rs[2] + rs[3];
    const float inv = 1.0f / s;
    ushort4 h0, h1;
    h0.x = f2bf(v0.x * inv); h0.y = f2bf(v0.y * inv);
    h0.z = f2bf(v0.z * inv); h0.w = f2bf(v0.w * inv);
    h1.x = f2bf(v1.x * inv); h1.y = f2bf(v1.y * inv);
    h1.z = f2bf(v1.z * inv); h1.w = f2bf(v1.w * inv);
    u16* o = Ph + (size_t)row * 2048;
    ((ushort4*)o)[threadIdx.x] = h0;
    ((ushort4*)o)[threadIdx.x + 256] = h1;
}

// ================= fallback: fp32 path (rounds 6-7, passing) =================
__launch_bounds__(256)
__global__ void rel_l1(const float* __restrict__ relations, const float* __restrict__ w1,
                       const float* __restrict__ b1, float* __restrict__ tmp) {
    const int s = blockIdx.x;
    const int d = threadIdx.x * 4;
    float4 rr = *(const float4*)(relations + s * 4);
    float4 w0 = *(const float4*)(w1 + 0 * 1024 + d);
    float4 w1r = *(const float4*)(w1 + 1 * 1024 + d);
    float4 w2r = *(const float4*)(w1 + 2 * 1024 + d);
    float4 w3r = *(const float4*)(w1 + 3 * 1024 + d);
    float4 bb = *(const float4*)(b1 + d);
    float o0 = fmaxf(rr.x * w0.x + rr.y * w1r.x + rr.z * w2r.x + rr.w * w3r.x + bb.x, 0.f);
    float o1 = fmaxf(rr.x * w0.y + rr.y * w1r.y + rr.z * w2r.y + rr.w * w3r.y + bb.y, 0.f);
    float o2 = fmaxf(rr.x * w0.z + rr.y * w1r.z + rr.z * w2r.z + rr.w * w3r.z + bb.z, 0.f);
    float o3 = fmaxf(rr.x * w0.w + rr.y * w1r.w + rr.z * w2r.w + rr.w * w3r.w + bb.w, 0.f);
    *(float4*)&tmp[(size_t)s * 1024 + d] = make_float4(o0, o1, o2, o3);
}

__launch_bounds__(256)
__global__ void softmax_rows(float* __restrict__ P) {
    const int row = blockIdx.x;
    float* p = P + (size_t)row * 2048;
    float4 v0 = ((const float4*)p)[threadIdx.x];
    float4 v1 = ((const float4*)p)[threadIdx.x + 256];
    float m = fmaxf(fmaxf(fmaxf(v0.x, v0.y), fmaxf(v0.z, v0.w)),
                    fmaxf(fmaxf(v1.x, v1.y), fmaxf(v1.z, v1.w)));
#pragma unroll
    for (int off = 32; off; off >>= 1) m = fmaxf(m, __shfl_xor(m, off));
    __shared__ float rm[4], rs[4];
    const int wave = threadIdx.x >> 6;
    if ((threadIdx.x & 63) == 0) rm[wave] = m;
    __syncthreads();
    m = fmaxf(fmaxf(rm[0], rm[1]), fmaxf(rm[2], rm[3]));
    v0.x = __expf(v0.x - m); v0.y = __expf(v0.y - m);
    v0.z = __expf(v0.z - m); v0.w = __expf(v0.w - m);
    v1.x = __expf(v1.x - m); v1.y = __expf(v1.y - m);
    v1.z = __expf(v1.z - m); v1.w = __expf(v1.w - m);
    float s = v0.x + v0.y + v0.z + v0.w + v1.x + v1.y + v1.z + v1.w;
#pragma unroll
    for (int off = 32; off; off >>= 1) s += __shfl_xor(s, off);
    if ((threadIdx.x & 63) == 0) rs[wave] = s;
    __syncthreads();
    s = rs[0] + rs[1] + rs[2] + rs[3];
    const float inv = 1.0f / s;
    v0.x *= inv; v0.y *= inv; v0.z *= inv; v0.w *= inv;
    v1.x *= inv; v1.y *= inv; v1.z *= inv; v1.w *= inv;
    ((float4*)p)[threadIdx.x] = v0;
    ((float4*)p)[threadIdx.x + 256] = v1;
}

constexpr int FBM = 64, FBN = 64, FBK = 16;

template<int MODE, bool ACC, bool TRC>
__launch_bounds__(256)
__global__ void gemm64(const float* __restrict__ A, const float* __restrict__ B,
                       float* __restrict__ C, const float* __restrict__ bias,
                       int M, int N, int K, int lda, int ldb, int ldc,
                       int head, size_t boff) {
    __shared__ float As[FBK][FBM + 4];
    __shared__ float Bs[FBK][FBN + 4];
    const int tid = threadIdx.x;
    const int tx = tid & 15;
    const int ty = tid >> 4;
    const int m0 = blockIdx.y * FBM;
    const int n0 = blockIdx.x * FBN;
    size_t bofft = boff;
    if (MODE == 2) bofft += (size_t)(m0 >> 8) * 1024 * 1024;
    const int ar = tid >> 2;
    const int ac = (tid & 3) << 2;
    int grow = m0 + ar;
    if (MODE == 2) grow = ((grow & 255) << 3) + head;
    const size_t abase = (size_t)grow * lda + ac;
    const int br = tid >> 4;
    const int bc = (tid & 15) << 2;
    const size_t bbase = bofft + (size_t)br * ldb + n0 + bc;
    float acc[4][4];
#pragma unroll
    for (int i = 0; i < 4; ++i)
#pragma unroll
        for (int j = 0; j < 4; ++j) acc[i][j] = 0.f;
    for (int k0 = 0; k0 < K; k0 += FBK) {
        float4 va = *(const float4*)(A + abase + k0);
        float4 vb = *(const float4*)(B + bbase + (size_t)k0 * ldb);
        As[ac + 0][ar] = va.x; As[ac + 1][ar] = va.y;
        As[ac + 2][ar] = va.z; As[ac + 3][ar] = va.w;
        *(float4*)&Bs[br][bc] = vb;
        __syncthreads();
#pragma unroll
        for (int k = 0; k < FBK; ++k) {
            float a[4], b[4];
            *(float4*)&a[0] = *(const float4*)&As[k][ty * 4];
            *(float4*)&b[0] = *(const float4*)&Bs[k][tx * 4];
#pragma unroll
            for (int i = 0; i < 4; ++i)
#pragma unroll
                for (int j = 0; j < 4; ++j)
                    acc[i][j] = fmaf(a[i], b[j], acc[i][j]);
        }
        __syncthreads();
    }
    if (TRC) {
#pragma unroll
        for (int j = 0; j < 4; ++j) {
            int cn = n0 + tx * 4 + j;
            size_t cidx = (size_t)cn * ldc + m0 + ty * 4;
            *(float4*)&C[cidx] = make_float4(acc[0][j], acc[1][j], acc[2][j], acc[3][j]);
        }
    } else {
        float bv[4] = {0.f, 0.f, 0.f, 0.f};
        if (bias) {
#pragma unroll
            for (int j = 0; j < 4; ++j) bv[j] = bias[n0 + tx * 4 + j];
        }
#pragma unroll
        for (int i = 0; i < 4; ++i) {
            int cm = m0 + ty * 4 + i;
            size_t cidx = (size_t)cm * ldc + n0 + tx * 4;
            float4 o = make_float4(acc[i][0] + bv[0], acc[i][1] + bv[1],
                                   acc[i][2] + bv[2], acc[i][3] + bv[3]);
            if (ACC) {
                float4 old = *(const float4*)&C[cidx];
                o.x += old.x; o.y += old.y; o.z += old.z; o.w += old.w;
            }
            *(float4*)&C[cidx] = o;
        }
    }
}

extern "C" void kernel_launch(void* const* d_in, const int* in_sizes, int n_in,
                              void* d_out, int out_size, void* d_ws, size_t ws_size,
                              hipStream_t stream) {
    const float* x      = (const float*)d_in[0];
    const float* rels   = (const float*)d_in[1];
    const float* re_w1  = (const float*)d_in[2];
    const float* re_b1  = (const float*)d_in[3];
    const float* re_w2  = (const float*)d_in[4];
    const float* re_b2  = (const float*)d_in[5];
    const float* attn_w = (const float*)d_in[6];
    const float* out_w  = (const float*)d_in[7];
    const float* out_b  = (const float*)d_in[8];
    float* out = (float*)d_out;

    bool dims_ok = (n_in == 9) &&
        in_sizes[0] == 2097152 && in_sizes[1] == 8192 && in_sizes[2] == 4096 &&
        in_sizes[3] == 1024 && in_sizes[4] == 1048576 && in_sizes[5] == 1024 &&
        in_sizes[6] == 8388608 && in_sizes[7] == 8388608 && in_sizes[8] == 1024 &&
        out_size == 2097152;
    const size_t MB = 1024 * 1024;
    if (!dims_ok || ws_size < 40 * MB) {
        float code = 16384.f + (dims_ok ? 0.f : 2048.f) + 1024.f;
        diag_k<<<dim3((out_size + 255) / 256), 256, 0, stream>>>(out, out_size, code);
        return;
    }

    if (ws_size >= 72 * MB) {
        char* W = (char*)d_ws;
        u16* xh    = (u16*)(W);
        u16* xl    = (u16*)(W + 4 * MB);
        u16* relh  = (u16*)(W + 8 * MB);
        u16* rell  = (u16*)(W + 12 * MB);
        u16* awTh  = (u16*)(W + 16 * MB);
        u16* awTl  = (u16*)(W + 32 * MB);
        u16* Kph   = (u16*)(W + 48 * MB);
        u16* Kpl   = (u16*)(W + 52 * MB);
        u16* Ph    = (u16*)(W + 48 * MB);
        float* L   = (float*)(W + 56 * MB);
        u16* tmph  = (u16*)(W + 56 * MB);
        u16* tmpl  = (u16*)(W + 60 * MB);
        u16* rw2Th = (u16*)(W + 64 * MB);
        u16* rw2Tl = (u16*)(W + 66 * MB);
        u16* ctxh  = (u16*)(W + 56 * MB);
        u16* owTh  = (u16*)(W + 60 * MB);
        const bool hoist_xT = (ws_size >= 76 * MB);
        u16* xTh = hoist_xT ? (u16*)(W + 72 * MB) : (u16*)(W + 62 * MB);

        expand_pair<<<dim3(2048), 256, 0, stream>>>(x, xh, xl);
        rel_l1_pair<<<dim3(2048), 256, 0, stream>>>(rels, re_w1, re_b1, tmph, tmpl);
        tr_pair<<<dim3(32, 32, 1), 256, 0, stream>>>(re_w2, rw2Th, rw2Tl, 1024, 1024, 0, 0);
        // rel = tmp @ re_w2 + re_b2 -> pair
        mg4<2, 2, 0, 3, 3><<<dim3(16, 32), 256, 0, stream>>>(
            tmph, tmpl, rw2Th, rw2Tl, relh, rell, re_b2, 1024, 1024, 1024, 1024, 0);
        tr_pair<<<dim3(32, 32, 8), 256, 0, stream>>>(attn_w, awTh, awTl, 1024, 1024,
                                                     1048576, 1048576);
        if (hoist_xT)
            tr_pair<<<dim3(32, 64, 1), 256, 0, stream>>>(x, xTh, nullptr, 2048, 1024, 0, 0);
        init_out<<<dim3(2048), 256, 0, stream>>>(out_b, out);
        for (int h = 0; h < 8; ++h) {
            // Kp[t][d] = x[8*(t&255)+h] @ attn_w[t>>8]
            mg4<2, 2, 2, 3, 3><<<dim3(16, 32), 256, 0, stream>>>(
                xh, xl, awTh, awTl, Kph, Kpl, nullptr, 1024, 1024, 1024, 1024, h);
            // L = rel @ Kp^T
            mg4<4, 2, 0, 3, 0><<<dim3(32, 16), 256, 0, stream>>>(
                relh, rell, Kph, Kpl, L, nullptr, nullptr, 1024, 1024, 1024, 2048, 0);
            softmax_hi<<<dim3(2048), 256, 0, stream>>>(L, Ph);
            tr_pair<<<dim3(32, 32, 1), 256, 0, stream>>>(
                out_w + (size_t)h * MB, owTh, nullptr, 1024, 1024, 0, 0);
            if (!hoist_xT)
                tr_pair<<<dim3(32, 64, 1), 256, 0, stream>>>(x, xTh, nullptr, 2048, 1024, 0, 0);
            // ctx = P @ x   (B = xT [d][t])
            mg4<2, 2, 0, 1, 2><<<dim3(16, 32), 256, 0, stream>>>(
                Ph, nullptr, xTh, nullptr, ctxh, nullptr, nullptr, 2048, 2048, 2048, 1024, 0);
            // out += ctx @ out_w[h]   (B = owT [n][d])
            mg4<2, 2, 0, 1, 1><<<dim3(16, 32), 256, 0, stream>>>(
                ctxh, nullptr, owTh, nullptr, out, nullptr, nullptr, 1024, 1024, 1024, 1024, 0);
        }
        return;
    }

    // ================= fallback: fp32 path =================
    float* ws  = (float*)d_ws;
    float* rel = ws;
    float* KpT = rel + 2097152;
    float* ctx = KpT + 2097152;
    float* L   = ctx + 2097152;
    float* tmp = L;

    rel_l1<<<dim3(2048), dim3(256), 0, stream>>>(rels, re_w1, re_b1, tmp);
    gemm64<0, false, false><<<dim3(16, 32), 256, 0, stream>>>(
        tmp, re_w2, rel, re_b2, 2048, 1024, 1024, 1024, 1024, 1024, 0, 0);
    init_out<<<dim3(2048), dim3(256), 0, stream>>>(out_b, out);
    for (int h = 0; h < 8; ++h) {
        gemm64<2, false, true><<<dim3(16, 32), 256, 0, stream>>>(
            x, attn_w, KpT, nullptr, 2048, 1024, 1024, 1024, 1024, 2048, h, 0);
        gemm64<0, false, false><<<dim3(32, 32), 256, 0, stream>>>(
            rel, KpT, L, nullptr, 2048, 2048, 1024, 1024, 2048, 2048, 0, 0);
        softmax_rows<<<dim3(2048), 256, 0, stream>>>(L);
        gemm64<0, false, false><<<dim3(16, 32), 256, 0, stream>>>(
            L, x, ctx, nullptr, 2048, 1024, 2048, 2048, 1024, 1024, 0, 0);
        gemm64<0, true, false><<<dim3(16, 32), 256, 0, stream>>>(
            ctx, out_w, out, nullptr, 2048, 1024, 1024, 1024, 1024, 1024,
            0, (size_t)h * 1024 * 1024);
    }
}

// Round 13
// 1173.013 us; speedup vs baseline: 1.2587x; 1.1694x over previous
//
#include <hip/hip_runtime.h>

// RelationAwareAttention: B=1, S=2048, D=1024, H=8. fp32 in / fp32 out.
// Raw reshape semantics: key(h,t) = x[8*(t&255)+h] @ attn_w[t>>8]
// Round-13: REVERT to round-10 mg2 (best measured: 1199us; rounds 11/12's
// mg3/mg4 bodies regressed despite 0 bank conflicts -> conflicts not the
// bottleneck, grid starvation is). Two isolated changes:
//   1. logits tile 128x64 -> 64x64 (grid 512->1024 blocks = 4/CU)
//   2. batch aw transposes (z=8) + hoist x-transpose (gated ws>=76MB)
// Split-bf16: PROD3 (AhBh+AhBl+AlBh) rel/Kp/logits; PROD1 ctx/outproj.
// ws map (72 MiB + optional 4):
//   0 xh 4 | 4 xl | 8 relh | 12 rell | 16 awTh 16 | 32 awTl 16
//   48 Kp pair 8 (Ph aliases after logits) | 56 L 16
//   L aliases: tmph@56 tmpl@60 rw2Th@64 rw2Tl@66 (pre-loop);
//              ctxh@56 owTh@60 xTh@62 (post-softmax, per-head)
//   ws>=76MB: persistent xTh@72 (computed once).
// Fallback: ws<72M -> fp32 gemm64 path; ws<40M -> sentinel.

typedef unsigned short u16;
typedef short s16x8 __attribute__((ext_vector_type(8)));
typedef float f32x4 __attribute__((ext_vector_type(4)));

__device__ __forceinline__ float bf2f(u16 u) {
    union { unsigned int i; float f; } v; v.i = ((unsigned int)u) << 16; return v.f;
}
__device__ __forceinline__ u16 f2bf(float f) {
    unsigned int x = __float_as_uint(f);
    unsigned int r = x + 0x7fffu + ((x >> 16) & 1u);
    return (u16)(r >> 16);
}

__launch_bounds__(256)
__global__ void diag_k(float* __restrict__ out, int n, float code) {
    int i = blockIdx.x * 256 + threadIdx.x;
    if (i < n) out[i] = (i == 0) ? code : 0.f;
}

__launch_bounds__(256)
__global__ void expand_pair(const float* __restrict__ src, u16* __restrict__ hi,
                            u16* __restrict__ lo) {
    const size_t i = ((size_t)blockIdx.x * 256 + threadIdx.x) * 4;
    float4 v = *(const float4*)&src[i];
    ushort4 h, l;
    h.x = f2bf(v.x); l.x = f2bf(v.x - bf2f(h.x));
    h.y = f2bf(v.y); l.y = f2bf(v.y - bf2f(h.y));
    h.z = f2bf(v.z); l.z = f2bf(v.z - bf2f(h.z));
    h.w = f2bf(v.w); l.w = f2bf(v.w - bf2f(h.w));
    *(ushort4*)&hi[i] = h;
    *(ushort4*)&lo[i] = l;
}

// transpose fp32 [R][C] -> bf16 hi(/lo) [C][R]; grid.z slabs for batching
__launch_bounds__(256)
__global__ void tr_pair(const float* __restrict__ src0, u16* __restrict__ dh0,
                        u16* __restrict__ dl0, int R, int C,
                        size_t src_z, size_t dst_z) {
    __shared__ float T[32][33];
    const float* src = src0 + (size_t)blockIdx.z * src_z;
    u16* dh = dh0 + (size_t)blockIdx.z * dst_z;
    u16* dl = dl0 ? dl0 + (size_t)blockIdx.z * dst_z : nullptr;
    const int bx = blockIdx.x, by = blockIdx.y;
    const int rr = threadIdx.x >> 3;
    const int cc = (threadIdx.x & 7) * 4;
    float4 v = *(const float4*)(src + (size_t)(by * 32 + rr) * C + bx * 32 + cc);
    T[rr][cc] = v.x; T[rr][cc + 1] = v.y; T[rr][cc + 2] = v.z; T[rr][cc + 3] = v.w;
    __syncthreads();
    float o0 = T[cc + 0][rr], o1 = T[cc + 1][rr], o2 = T[cc + 2][rr], o3 = T[cc + 3][rr];
    ushort4 h;
    h.x = f2bf(o0); h.y = f2bf(o1); h.z = f2bf(o2); h.w = f2bf(o3);
    size_t di = (size_t)(bx * 32 + rr) * R + by * 32 + cc;
    *(ushort4*)&dh[di] = h;
    if (dl) {
        ushort4 l;
        l.x = f2bf(o0 - bf2f(h.x)); l.y = f2bf(o1 - bf2f(h.y));
        l.z = f2bf(o2 - bf2f(h.z)); l.w = f2bf(o3 - bf2f(h.w));
        *(ushort4*)&dl[di] = l;
    }
}

__launch_bounds__(256)
__global__ void rel_l1_pair(const float* __restrict__ relations, const float* __restrict__ w1,
                            const float* __restrict__ b1, u16* __restrict__ th,
                            u16* __restrict__ tl) {
    const int s = blockIdx.x;
    const int d = threadIdx.x * 4;
    float4 rr = *(const float4*)(relations + s * 4);
    float4 w0 = *(const float4*)(w1 + 0 * 1024 + d);
    float4 w1r = *(const float4*)(w1 + 1 * 1024 + d);
    float4 w2r = *(const float4*)(w1 + 2 * 1024 + d);
    float4 w3r = *(const float4*)(w1 + 3 * 1024 + d);
    float4 bb = *(const float4*)(b1 + d);
    float o[4];
    o[0] = fmaxf(rr.x * w0.x + rr.y * w1r.x + rr.z * w2r.x + rr.w * w3r.x + bb.x, 0.f);
    o[1] = fmaxf(rr.x * w0.y + rr.y * w1r.y + rr.z * w2r.y + rr.w * w3r.y + bb.y, 0.f);
    o[2] = fmaxf(rr.x * w0.z + rr.y * w1r.z + rr.z * w2r.z + rr.w * w3r.z + bb.z, 0.f);
    o[3] = fmaxf(rr.x * w0.w + rr.y * w1r.w + rr.z * w2r.w + rr.w * w3r.w + bb.w, 0.f);
    ushort4 h, l;
    h.x = f2bf(o[0]); l.x = f2bf(o[0] - bf2f(h.x));
    h.y = f2bf(o[1]); l.y = f2bf(o[1] - bf2f(h.y));
    h.z = f2bf(o[2]); l.z = f2bf(o[2] - bf2f(h.z));
    h.w = f2bf(o[3]); l.w = f2bf(o[3] - bf2f(h.w));
    *(ushort4*)&th[(size_t)s * 1024 + d] = h;
    *(ushort4*)&tl[(size_t)s * 1024 + d] = l;
}

__launch_bounds__(256)
__global__ void init_out(const float* __restrict__ bias, float* __restrict__ oa) {
    const int s = blockIdx.x;
    const int d = threadIdx.x * 4;
    *(float4*)&oa[(size_t)s * 1024 + d] = *(const float4*)(bias + d);
}

// ============== MFMA GEMM v2 (round-10 exact): (MI*32)x64, BK=32, 4 waves ====
// A [M][K], B [N][K] both K-contiguous bf16.
// LDS chunk layout per 16-row block: chunk = (m&1) + 2*kb + 8*(m>>1).
// MODE 0: plain. MODE 2: A row remap 8*((m0+r)&255)+head, B offset (m0>>8)*1M.
// PROD 3: AhBh+AhBl+AlBh. PROD 1: AhBh.
// OUT 0: fp32 store; 1: fp32 +=; 2: bf16-hi store; 3: bf16 pair (+bias).
template<int MI, int MODE, int PROD, int OUT>
__launch_bounds__(256)
__global__ void mg2(const u16* __restrict__ Ah, const u16* __restrict__ Al,
                    const u16* __restrict__ Bh, const u16* __restrict__ Bl,
                    void* __restrict__ C, u16* __restrict__ C2,
                    const float* __restrict__ bias,
                    int K, int lda, int ldb, int ldc, int head) {
    __shared__ u16 sAh[MI * 1024];
    __shared__ u16 sBh[2048];
    __shared__ u16 sAl[(PROD == 3) ? MI * 1024 : 8];
    __shared__ u16 sBl[(PROD == 3) ? 2048 : 8];
    const int tid = threadIdx.x;
    const int m0 = blockIdx.y * (MI * 32);
    const int n0 = blockIdx.x * 64;
    const int w = tid >> 6, lane = tid & 63;
    const int wmB = (w >> 1) * MI;   // first m-block (16-rows) of this wave
    const int wnB = (w & 1) * 2;     // first n-block

    // frag offset within a 512-u16 block region:
    // m = lane&15, kb = lane>>4 -> chunk = (m&1) + 2*kb + 8*(m>>1)
    const int fo = (((lane & 1) + ((lane >> 4) << 1) + (((lane & 15) >> 1) << 3)) << 3);

    size_t bofft = 0;
    if (MODE == 2) bofft = (size_t)(m0 >> 8) * 1048576;

    f32x4 acc[MI][2];
#pragma unroll
    for (int i = 0; i < MI; ++i)
#pragma unroll
        for (int j = 0; j < 2; ++j) acc[i][j] = {0.f, 0.f, 0.f, 0.f};

    for (int k0 = 0; k0 < K; k0 += 32) {
        // ---- stage A: MI*128 chunks of 8 u16 ----
#pragma unroll
        for (int cb = 0; cb < MI * 128; cb += 256) {
            int c = cb + tid;
            int mb = c >> 6, cl = c & 63;
            int m = ((cl >> 3) << 1) | (cl & 1);
            int kb = (cl >> 1) & 3;
            int rloc = mb * 16 + m;
            int grow = (MODE == 2) ? ((((m0 + rloc) & 255) << 3) + head) : (m0 + rloc);
            size_t ga = (size_t)grow * lda + k0 + kb * 8;
            *(uint4*)&sAh[c * 8] = *(const uint4*)(Ah + ga);
            if (PROD == 3) *(uint4*)&sAl[c * 8] = *(const uint4*)(Al + ga);
        }
        // ---- stage B: 256 chunks ----
        {
            int c = tid;
            int nb = c >> 6, cl = c & 63;
            int n = ((cl >> 3) << 1) | (cl & 1);
            int kb = (cl >> 1) & 3;
            size_t ga = bofft + (size_t)(n0 + nb * 16 + n) * ldb + k0 + kb * 8;
            *(uint4*)&sBh[c * 8] = *(const uint4*)(Bh + ga);
            if (PROD == 3) *(uint4*)&sBl[c * 8] = *(const uint4*)(Bl + ga);
        }
        __syncthreads();
        // ---- frags + MFMA ----
        s16x8 bh0 = *(const s16x8*)&sBh[(wnB + 0) * 512 + fo];
        s16x8 bh1 = *(const s16x8*)&sBh[(wnB + 1) * 512 + fo];
        s16x8 bl0, bl1;
        if (PROD == 3) {
            bl0 = *(const s16x8*)&sBl[(wnB + 0) * 512 + fo];
            bl1 = *(const s16x8*)&sBl[(wnB + 1) * 512 + fo];
        }
#pragma unroll
        for (int i = 0; i < MI; ++i) {
            s16x8 ah = *(const s16x8*)&sAh[(wmB + i) * 512 + fo];
            acc[i][0] = __builtin_amdgcn_mfma_f32_16x16x32_bf16(ah, bh0, acc[i][0], 0, 0, 0);
            acc[i][1] = __builtin_amdgcn_mfma_f32_16x16x32_bf16(ah, bh1, acc[i][1], 0, 0, 0);
            if (PROD == 3) {
                s16x8 al = *(const s16x8*)&sAl[(wmB + i) * 512 + fo];
                acc[i][0] = __builtin_amdgcn_mfma_f32_16x16x32_bf16(ah, bl0, acc[i][0], 0, 0, 0);
                acc[i][1] = __builtin_amdgcn_mfma_f32_16x16x32_bf16(ah, bl1, acc[i][1], 0, 0, 0);
                acc[i][0] = __builtin_amdgcn_mfma_f32_16x16x32_bf16(al, bh0, acc[i][0], 0, 0, 0);
                acc[i][1] = __builtin_amdgcn_mfma_f32_16x16x32_bf16(al, bh1, acc[i][1], 0, 0, 0);
            }
        }
        __syncthreads();
    }

    // ---- epilogue: C col=lane&15, row=(lane>>4)*4+reg (verified m89/m91) ----
    const int cc = lane & 15, q = lane >> 4;
#pragma unroll
    for (int i = 0; i < MI; ++i) {
#pragma unroll
        for (int j = 0; j < 2; ++j) {
            const int mb = m0 + (wmB + i) * 16 + q * 4;
            const int nb = n0 + (wnB + j) * 16 + cc;
            if (OUT == 0) {
                float* Cf = (float*)C;
#pragma unroll
                for (int r = 0; r < 4; ++r)
                    Cf[(size_t)(mb + r) * ldc + nb] = acc[i][j][r];
            } else if (OUT == 1) {
                float* Cf = (float*)C;
#pragma unroll
                for (int r = 0; r < 4; ++r)
                    Cf[(size_t)(mb + r) * ldc + nb] += acc[i][j][r];
            } else if (OUT == 2) {
                u16* Ch = (u16*)C;
#pragma unroll
                for (int r = 0; r < 4; ++r)
                    Ch[(size_t)(mb + r) * ldc + nb] = f2bf(acc[i][j][r]);
            } else {  // OUT == 3
                u16* Ch = (u16*)C;
                float bv = bias ? bias[nb] : 0.f;
#pragma unroll
                for (int r = 0; r < 4; ++r) {
                    float v = acc[i][j][r] + bv;
                    u16 h = f2bf(v);
                    Ch[(size_t)(mb + r) * ldc + nb] = h;
                    C2[(size_t)(mb + r) * ldc + nb] = f2bf(v - bf2f(h));
                }
            }
        }
    }
}

// ---------------- softmax: fp32 L row -> bf16-hi P row ----------------
__launch_bounds__(256)
__global__ void softmax_hi(const float* __restrict__ L, u16* __restrict__ Ph) {
    const int row = blockIdx.x;
    const float* p = L + (size_t)row * 2048;
    float4 v0 = ((const float4*)p)[threadIdx.x];
    float4 v1 = ((const float4*)p)[threadIdx.x + 256];
    float m = fmaxf(fmaxf(fmaxf(v0.x, v0.y), fmaxf(v0.z, v0.w)),
                    fmaxf(fmaxf(v1.x, v1.y), fmaxf(v1.z, v1.w)));
#pragma unroll
    for (int off = 32; off; off >>= 1) m = fmaxf(m, __shfl_xor(m, off));
    __shared__ float rm[4], rs[4];
    const int wave = threadIdx.x >> 6;
    if ((threadIdx.x & 63) == 0) rm[wave] = m;
    __syncthreads();
    m = fmaxf(fmaxf(rm[0], rm[1]), fmaxf(rm[2], rm[3]));
    v0.x = __expf(v0.x - m); v0.y = __expf(v0.y - m);
    v0.z = __expf(v0.z - m); v0.w = __expf(v0.w - m);
    v1.x = __expf(v1.x - m); v1.y = __expf(v1.y - m);
    v1.z = __expf(v1.z - m); v1.w = __expf(v1.w - m);
    float s = v0.x + v0.y + v0.z + v0.w + v1.x + v1.y + v1.z + v1.w;
#pragma unroll
    for (int off = 32; off; off >>= 1) s += __shfl_xor(s, off);
    if ((threadIdx.x & 63) == 0) rs[wave] = s;
    __syncthreads();
    s = rs[0] + rs[1] + rs[2] + rs[3];
    const float inv = 1.0f / s;
    ushort4 h0, h1;
    h0.x = f2bf(v0.x * inv); h0.y = f2bf(v0.y * inv);
    h0.z = f2bf(v0.z * inv); h0.w = f2bf(v0.w * inv);
    h1.x = f2bf(v1.x * inv); h1.y = f2bf(v1.y * inv);
    h1.z = f2bf(v1.z * inv); h1.w = f2bf(v1.w * inv);
    u16* o = Ph + (size_t)row * 2048;
    ((ushort4*)o)[threadIdx.x] = h0;
    ((ushort4*)o)[threadIdx.x + 256] = h1;
}

// ================= fallback: fp32 path (rounds 6-7, passing) =================
__launch_bounds__(256)
__global__ void rel_l1(const float* __restrict__ relations, const float* __restrict__ w1,
                       const float* __restrict__ b1, float* __restrict__ tmp) {
    const int s = blockIdx.x;
    const int d = threadIdx.x * 4;
    float4 rr = *(const float4*)(relations + s * 4);
    float4 w0 = *(const float4*)(w1 + 0 * 1024 + d);
    float4 w1r = *(const float4*)(w1 + 1 * 1024 + d);
    float4 w2r = *(const float4*)(w1 + 2 * 1024 + d);
    float4 w3r = *(const float4*)(w1 + 3 * 1024 + d);
    float4 bb = *(const float4*)(b1 + d);
    float o0 = fmaxf(rr.x * w0.x + rr.y * w1r.x + rr.z * w2r.x + rr.w * w3r.x + bb.x, 0.f);
    float o1 = fmaxf(rr.x * w0.y + rr.y * w1r.y + rr.z * w2r.y + rr.w * w3r.y + bb.y, 0.f);
    float o2 = fmaxf(rr.x * w0.z + rr.y * w1r.z + rr.z * w2r.z + rr.w * w3r.z + bb.z, 0.f);
    float o3 = fmaxf(rr.x * w0.w + rr.y * w1r.w + rr.z * w2r.w + rr.w * w3r.w + bb.w, 0.f);
    *(float4*)&tmp[(size_t)s * 1024 + d] = make_float4(o0, o1, o2, o3);
}

__launch_bounds__(256)
__global__ void softmax_rows(float* __restrict__ P) {
    const int row = blockIdx.x;
    float* p = P + (size_t)row * 2048;
    float4 v0 = ((const float4*)p)[threadIdx.x];
    float4 v1 = ((const float4*)p)[threadIdx.x + 256];
    float m = fmaxf(fmaxf(fmaxf(v0.x, v0.y), fmaxf(v0.z, v0.w)),
                    fmaxf(fmaxf(v1.x, v1.y), fmaxf(v1.z, v1.w)));
#pragma unroll
    for (int off = 32; off; off >>= 1) m = fmaxf(m, __shfl_xor(m, off));
    __shared__ float rm[4], rs[4];
    const int wave = threadIdx.x >> 6;
    if ((threadIdx.x & 63) == 0) rm[wave] = m;
    __syncthreads();
    m = fmaxf(fmaxf(rm[0], rm[1]), fmaxf(rm[2], rm[3]));
    v0.x = __expf(v0.x - m); v0.y = __expf(v0.y - m);
    v0.z = __expf(v0.z - m); v0.w = __expf(v0.w - m);
    v1.x = __expf(v1.x - m); v1.y = __expf(v1.y - m);
    v1.z = __expf(v1.z - m); v1.w = __expf(v1.w - m);
    float s = v0.x + v0.y + v0.z + v0.w + v1.x + v1.y + v1.z + v1.w;
#pragma unroll
    for (int off = 32; off; off >>= 1) s += __shfl_xor(s, off);
    if ((threadIdx.x & 63) == 0) rs[wave] = s;
    __syncthreads();
    s = rs[0] + rs[1] + rs[2] + rs[3];
    const float inv = 1.0f / s;
    v0.x *= inv; v0.y *= inv; v0.z *= inv; v0.w *= inv;
    v1.x *= inv; v1.y *= inv; v1.z *= inv; v1.w *= inv;
    ((float4*)p)[threadIdx.x] = v0;
    ((float4*)p)[threadIdx.x + 256] = v1;
}

constexpr int FBM = 64, FBN = 64, FBK = 16;

template<int MODE, bool ACC, bool TRC>
__launch_bounds__(256)
__global__ void gemm64(const float* __restrict__ A, const float* __restrict__ B,
                       float* __restrict__ C, const float* __restrict__ bias,
                       int M, int N, int K, int lda, int ldb, int ldc,
                       int head, size_t boff) {
    __shared__ float As[FBK][FBM + 4];
    __shared__ float Bs[FBK][FBN + 4];
    const int tid = threadIdx.x;
    const int tx = tid & 15;
    const int ty = tid >> 4;
    const int m0 = blockIdx.y * FBM;
    const int n0 = blockIdx.x * FBN;
    size_t bofft = boff;
    if (MODE == 2) bofft += (size_t)(m0 >> 8) * 1024 * 1024;
    const int ar = tid >> 2;
    const int ac = (tid & 3) << 2;
    int grow = m0 + ar;
    if (MODE == 2) grow = ((grow & 255) << 3) + head;
    const size_t abase = (size_t)grow * lda + ac;
    const int br = tid >> 4;
    const int bc = (tid & 15) << 2;
    const size_t bbase = bofft + (size_t)br * ldb + n0 + bc;
    float acc[4][4];
#pragma unroll
    for (int i = 0; i < 4; ++i)
#pragma unroll
        for (int j = 0; j < 4; ++j) acc[i][j] = 0.f;
    for (int k0 = 0; k0 < K; k0 += FBK) {
        float4 va = *(const float4*)(A + abase + k0);
        float4 vb = *(const float4*)(B + bbase + (size_t)k0 * ldb);
        As[ac + 0][ar] = va.x; As[ac + 1][ar] = va.y;
        As[ac + 2][ar] = va.z; As[ac + 3][ar] = va.w;
        *(float4*)&Bs[br][bc] = vb;
        __syncthreads();
#pragma unroll
        for (int k = 0; k < FBK; ++k) {
            float a[4], b[4];
            *(float4*)&a[0] = *(const float4*)&As[k][ty * 4];
            *(float4*)&b[0] = *(const float4*)&Bs[k][tx * 4];
#pragma unroll
            for (int i = 0; i < 4; ++i)
#pragma unroll
                for (int j = 0; j < 4; ++j)
                    acc[i][j] = fmaf(a[i], b[j], acc[i][j]);
        }
        __syncthreads();
    }
    if (TRC) {
#pragma unroll
        for (int j = 0; j < 4; ++j) {
            int cn = n0 + tx * 4 + j;
            size_t cidx = (size_t)cn * ldc + m0 + ty * 4;
            *(float4*)&C[cidx] = make_float4(acc[0][j], acc[1][j], acc[2][j], acc[3][j]);
        }
    } else {
        float bv[4] = {0.f, 0.f, 0.f, 0.f};
        if (bias) {
#pragma unroll
            for (int j = 0; j < 4; ++j) bv[j] = bias[n0 + tx * 4 + j];
        }
#pragma unroll
        for (int i = 0; i < 4; ++i) {
            int cm = m0 + ty * 4 + i;
            size_t cidx = (size_t)cm * ldc + n0 + tx * 4;
            float4 o = make_float4(acc[i][0] + bv[0], acc[i][1] + bv[1],
                                   acc[i][2] + bv[2], acc[i][3] + bv[3]);
            if (ACC) {
                float4 old = *(const float4*)&C[cidx];
                o.x += old.x; o.y += old.y; o.z += old.z; o.w += old.w;
            }
            *(float4*)&C[cidx] = o;
        }
    }
}

extern "C" void kernel_launch(void* const* d_in, const int* in_sizes, int n_in,
                              void* d_out, int out_size, void* d_ws, size_t ws_size,
                              hipStream_t stream) {
    const float* x      = (const float*)d_in[0];
    const float* rels   = (const float*)d_in[1];
    const float* re_w1  = (const float*)d_in[2];
    const float* re_b1  = (const float*)d_in[3];
    const float* re_w2  = (const float*)d_in[4];
    const float* re_b2  = (const float*)d_in[5];
    const float* attn_w = (const float*)d_in[6];
    const float* out_w  = (const float*)d_in[7];
    const float* out_b  = (const float*)d_in[8];
    float* out = (float*)d_out;

    bool dims_ok = (n_in == 9) &&
        in_sizes[0] == 2097152 && in_sizes[1] == 8192 && in_sizes[2] == 4096 &&
        in_sizes[3] == 1024 && in_sizes[4] == 1048576 && in_sizes[5] == 1024 &&
        in_sizes[6] == 8388608 && in_sizes[7] == 8388608 && in_sizes[8] == 1024 &&
        out_size == 2097152;
    const size_t MB = 1024 * 1024;
    if (!dims_ok || ws_size < 40 * MB) {
        float code = 16384.f + (dims_ok ? 0.f : 2048.f) + 1024.f;
        diag_k<<<dim3((out_size + 255) / 256), 256, 0, stream>>>(out, out_size, code);
        return;
    }

    if (ws_size >= 72 * MB) {
        char* W = (char*)d_ws;
        u16* xh    = (u16*)(W);
        u16* xl    = (u16*)(W + 4 * MB);
        u16* relh  = (u16*)(W + 8 * MB);
        u16* rell  = (u16*)(W + 12 * MB);
        u16* awTh  = (u16*)(W + 16 * MB);
        u16* awTl  = (u16*)(W + 32 * MB);
        u16* Kph   = (u16*)(W + 48 * MB);
        u16* Kpl   = (u16*)(W + 52 * MB);
        u16* Ph    = (u16*)(W + 48 * MB);
        float* L   = (float*)(W + 56 * MB);
        u16* tmph  = (u16*)(W + 56 * MB);
        u16* tmpl  = (u16*)(W + 60 * MB);
        u16* rw2Th = (u16*)(W + 64 * MB);
        u16* rw2Tl = (u16*)(W + 66 * MB);
        u16* ctxh  = (u16*)(W + 56 * MB);
        u16* owTh  = (u16*)(W + 60 * MB);
        const bool hoist_xT = (ws_size >= 76 * MB);
        u16* xTh = hoist_xT ? (u16*)(W + 72 * MB) : (u16*)(W + 62 * MB);

        expand_pair<<<dim3(2048), 256, 0, stream>>>(x, xh, xl);
        rel_l1_pair<<<dim3(2048), 256, 0, stream>>>(rels, re_w1, re_b1, tmph, tmpl);
        tr_pair<<<dim3(32, 32, 1), 256, 0, stream>>>(re_w2, rw2Th, rw2Tl, 1024, 1024, 0, 0);
        // rel = tmp @ re_w2 + re_b2 -> pair
        mg2<2, 0, 3, 3><<<dim3(16, 32), 256, 0, stream>>>(
            tmph, tmpl, rw2Th, rw2Tl, relh, rell, re_b2, 1024, 1024, 1024, 1024, 0);
        // all 8 attn_w transposes batched
        tr_pair<<<dim3(32, 32, 8), 256, 0, stream>>>(attn_w, awTh, awTl, 1024, 1024,
                                                     1048576, 1048576);
        if (hoist_xT)
            tr_pair<<<dim3(32, 64, 1), 256, 0, stream>>>(x, xTh, nullptr, 2048, 1024, 0, 0);
        init_out<<<dim3(2048), 256, 0, stream>>>(out_b, out);
        for (int h = 0; h < 8; ++h) {
            // Kp[t][d] = x[8*(t&255)+h] @ attn_w[t>>8]
            mg2<2, 2, 3, 3><<<dim3(16, 32), 256, 0, stream>>>(
                xh, xl, awTh, awTl, Kph, Kpl, nullptr, 1024, 1024, 1024, 1024, h);
            // L = rel @ Kp^T  (64x64 tiles: 1024 blocks = 4/CU)
            mg2<2, 0, 3, 0><<<dim3(32, 32), 256, 0, stream>>>(
                relh, rell, Kph, Kpl, L, nullptr, nullptr, 1024, 1024, 1024, 2048, 0);
            softmax_hi<<<dim3(2048), 256, 0, stream>>>(L, Ph);
            tr_pair<<<dim3(32, 32, 1), 256, 0, stream>>>(
                out_w + (size_t)h * MB, owTh, nullptr, 1024, 1024, 0, 0);
            if (!hoist_xT)
                tr_pair<<<dim3(32, 64, 1), 256, 0, stream>>>(x, xTh, nullptr, 2048, 1024, 0, 0);
            // ctx = P @ x   (B = xT [d][t])
            mg2<2, 0, 1, 2><<<dim3(16, 32), 256, 0, stream>>>(
                Ph, nullptr, xTh, nullptr, ctxh, nullptr, nullptr, 2048, 2048, 2048, 1024, 0);
            // out += ctx @ out_w[h]   (B = owT [n][d])
            mg2<2, 0, 1, 1><<<dim3(16, 32), 256, 0, stream>>>(
                ctxh, nullptr, owTh, nullptr, out, nullptr, nullptr, 1024, 1024, 1024, 1024, 0);
        }
        return;
    }

    // ================= fallback: fp32 path =================
    float* ws  = (float*)d_ws;
    float* rel = ws;
    float* KpT = rel + 2097152;
    float* ctx = KpT + 2097152;
    float* L   = ctx + 2097152;
    float* tmp = L;

    rel_l1<<<dim3(2048), dim3(256), 0, stream>>>(rels, re_w1, re_b1, tmp);
    gemm64<0, false, false><<<dim3(16, 32), 256, 0, stream>>>(
        tmp, re_w2, rel, re_b2, 2048, 1024, 1024, 1024, 1024, 1024, 0, 0);
    init_out<<<dim3(2048), dim3(256), 0, stream>>>(out_b, out);
    for (int h = 0; h < 8; ++h) {
        gemm64<2, false, true><<<dim3(16, 32), 256, 0, stream>>>(
            x, attn_w, KpT, nullptr, 2048, 1024, 1024, 1024, 1024, 2048, h, 0);
        gemm64<0, false, false><<<dim3(32, 32), 256, 0, stream>>>(
            rel, KpT, L, nullptr, 2048, 2048, 1024, 1024, 2048, 2048, 0, 0);
        softmax_rows<<<dim3(2048), 256, 0, stream>>>(L);
        gemm64<0, false, false><<<dim3(16, 32), 256, 0, stream>>>(
            L, x, ctx, nullptr, 2048, 1024, 2048, 2048, 1024, 1024, 0, 0);
        gemm64<0, true, false><<<dim3(16, 32), 256, 0, stream>>>(
            ctx, out_w, out, nullptr, 2048, 1024, 1024, 1024, 1024, 1024,
            0, (size_t)h * 1024 * 1024);
    }
}